// Round 7
// baseline (783.716 us; speedup 1.0000x reference)
//
#include <hip/hip_runtime.h>

#define NF 64        // IN_F == HID_F == 64
#define FILL_PASSES 8
#define NQ 8         // src slices
#define QSH 14       // slice = src >> 14 (16384 nodes = 2.1 MB bf16, L2-resident)

typedef unsigned short u16;

__device__ __forceinline__ float bf2f(unsigned h) {
    return __uint_as_float(h << 16);
}
__device__ __forceinline__ u16 f2bf(float x) {   // round-to-nearest-even
    unsigned u = __float_as_uint(x);
    return (u16)((u + 0x7FFFu + ((u >> 16) & 1u)) >> 16);
}

// ============ CSR build: counting sort by (dst, src_slice) ============

__global__ void count_kernel(const int* __restrict__ src, const int* __restrict__ dst,
                             int* __restrict__ cnt4, int E) {
    int e = blockIdx.x * blockDim.x + threadIdx.x;
    if (e < E) atomicAdd(&cnt4[dst[e] * NQ + (src[e] >> QSH)], 1);
}

__global__ void block_sums(const int* __restrict__ cnt, int* __restrict__ blocksum, int n) {
    int tid = threadIdx.x;
    int base_i = blockIdx.x * 1024 + tid * 4;
    int t = 0;
#pragma unroll
    for (int j = 0; j < 4; ++j) t += (base_i + j < n) ? cnt[base_i + j] : 0;
    __shared__ int s[256];
    s[tid] = t; __syncthreads();
    for (int off = 128; off > 0; off >>= 1) {
        if (tid < off) s[tid] += s[tid + off];
        __syncthreads();
    }
    if (tid == 0) blocksum[blockIdx.x] = s[0];
}

// single block, chunked: exclusive scan of nb block sums; rowptr4[n8] = E
__global__ void scan_blocksums(int* __restrict__ blocksum, int* __restrict__ rowptr4,
                               int nb, int n8, int E) {
    __shared__ int s[256];
    __shared__ int run;
    int tid = threadIdx.x;
    if (tid == 0) run = 0;
    __syncthreads();
    for (int c = 0; c < nb; c += 256) {
        int i = c + tid;
        int v = (i < nb) ? blocksum[i] : 0;
        s[tid] = v; __syncthreads();
        for (int off = 1; off < 256; off <<= 1) {
            int t = (tid >= off) ? s[tid - off] : 0;
            __syncthreads();
            s[tid] += t;
            __syncthreads();
        }
        if (i < nb) blocksum[i] = run + s[tid] - v;   // exclusive
        __syncthreads();
        if (tid == 255) run += s[255];
        __syncthreads();
    }
    if (tid == 0) rowptr4[n8] = E;
}

// per-element exclusive scan -> rowptr4; reset cnt4 to 0 (reused as cursor)
__global__ void scan_finalize(int* __restrict__ cnt4, const int* __restrict__ blocksum,
                              int* __restrict__ rowptr4, int n) {
    int tid = threadIdx.x;
    int base_i = blockIdx.x * 1024 + tid * 4;
    int v[4]; int tsum = 0;
#pragma unroll
    for (int j = 0; j < 4; ++j) { v[j] = (base_i + j < n) ? cnt4[base_i + j] : 0; tsum += v[j]; }
    __shared__ int s[256];
    s[tid] = tsum; __syncthreads();
    for (int off = 1; off < 256; off <<= 1) {
        int t = (tid >= off) ? s[tid - off] : 0;
        __syncthreads();
        s[tid] += t;
        __syncthreads();
    }
    int base = blocksum[blockIdx.x] + (s[tid] - tsum);
#pragma unroll
    for (int j = 0; j < 4; ++j) {
        int i = base_i + j;
        if (i < n) {
            rowptr4[i] = base;
            cnt4[i] = 0;
            base += v[j];
        }
    }
}

__global__ void dinv_kernel(const int* __restrict__ rowptr4, float* __restrict__ dinv, int n) {
    int d = blockIdx.x * blockDim.x + threadIdx.x;
    if (d < n) {
        int deg = rowptr4[(d + 1) * NQ] - rowptr4[d * NQ];
        dinv[d] = rsqrtf(fmaxf((float)deg, 1.0f));
    }
}

// multi-pass fill by dst range (write-merge) into (dst, slice)-sorted csr
__global__ void fill_kernel(const int* __restrict__ src, const int* __restrict__ dst,
                            const int* __restrict__ rowptr4, int* __restrict__ cursor4,
                            int* __restrict__ csr_src, int E, int N, int nchunks) {
    int b = blockIdx.x;
    int pass = b / nchunks;
    int chunk = b - pass * nchunks;
    int e = chunk * 256 + threadIdx.x;
    if (e >= E) return;
    int lo = (int)(((long long)N * pass) / FILL_PASSES);
    int hi = (int)(((long long)N * (pass + 1)) / FILL_PASSES);
    int d = dst[e];
    if (d >= lo && d < hi) {
        int sv = src[e];
        int idx = d * NQ + (sv >> QSH);
        int pos = rowptr4[idx] + atomicAdd(&cursor4[idx], 1);
        csr_src[pos] = sv;
    }
}

// ============ prescale: Y = bf16(X * dinv[node]) ============
__global__ void prescale(const float* __restrict__ X, const float* __restrict__ dinv,
                         u16* __restrict__ Y, int total4) {   // total4 = N*16
    int i = blockIdx.x * blockDim.x + threadIdx.x;
    if (i < total4) {
        int node = i >> 4;
        float dn = dinv[node];
        float4 v = ((const float4*)X)[i];
        ushort4 y;
        y.x = f2bf(v.x * dn); y.y = f2bf(v.y * dn);
        y.z = f2bf(v.z * dn); y.w = f2bf(v.w * dn);
        ((ushort4*)Y)[i] = y;
    }
}

// ============ SpMM gather (bf16 rows): wave/node, slice-phased for L2 locality ====
__launch_bounds__(256)
__global__ void spmm_bf16(const u16* __restrict__ Y, const int* __restrict__ rowptr4,
                          const int* __restrict__ csr_src, const float* __restrict__ dinv,
                          const float* __restrict__ Xprev, float* __restrict__ Xout,
                          u16* __restrict__ Yout, int n, int mode) {
    int node = (blockIdx.x * blockDim.x + threadIdx.x) >> 6;
    if (node >= n) return;
    int lane = threadIdx.x & 63;
    int g = lane >> 3;            // edge subgroup 0..7
    int fl = (lane & 7) << 3;     // feature offset 0,8,...,56

    float acc[8];
#pragma unroll
    for (int j = 0; j < 8; ++j) acc[j] = 0.f;

    // process the row slice-by-slice; co-resident waves stay in the same
    // ~2.1 MB gather slice -> L2 hits instead of L3 round-trips
#pragma unroll 1
    for (int q = 0; q < NQ; ++q) {
        int beg = rowptr4[node * NQ + q];
        int end = rowptr4[node * NQ + q + 1];
        for (int e0 = beg; e0 < end; e0 += 8) {
            int eg = e0 + g;
            if (eg < end) {
                int s = csr_src[eg];
                uint4 u = *(const uint4*)(Y + (size_t)s * NF + fl);
                acc[0] += bf2f(u.x & 0xFFFFu); acc[1] += bf2f(u.x >> 16);
                acc[2] += bf2f(u.y & 0xFFFFu); acc[3] += bf2f(u.y >> 16);
                acc[4] += bf2f(u.z & 0xFFFFu); acc[5] += bf2f(u.z >> 16);
                acc[6] += bf2f(u.w & 0xFFFFu); acc[7] += bf2f(u.w >> 16);
            }
        }
    }
#pragma unroll
    for (int m = 8; m <= 32; m <<= 1) {
#pragma unroll
        for (int j = 0; j < 8; ++j) acc[j] += __shfl_xor(acc[j], m, 64);
    }
    if (g == 0) {
        float dn = dinv[node];
        float r[8];
        if (mode == 1) {
#pragma unroll
            for (int j = 0; j < 8; ++j) r[j] = -acc[j] * dn;
            uint4 uy;
            uy.x = (unsigned)f2bf(r[0] * dn) | ((unsigned)f2bf(r[1] * dn) << 16);
            uy.y = (unsigned)f2bf(r[2] * dn) | ((unsigned)f2bf(r[3] * dn) << 16);
            uy.z = (unsigned)f2bf(r[4] * dn) | ((unsigned)f2bf(r[5] * dn) << 16);
            uy.w = (unsigned)f2bf(r[6] * dn) | ((unsigned)f2bf(r[7] * dn) << 16);
            *(uint4*)(Yout + (size_t)node * NF + fl) = uy;
        } else {
            float4 a = *(const float4*)(Xprev + (size_t)node * NF + fl);
            float4 b = *(const float4*)(Xprev + (size_t)node * NF + fl + 4);
            r[0] = -2.f * acc[0] * dn - a.x; r[1] = -2.f * acc[1] * dn - a.y;
            r[2] = -2.f * acc[2] * dn - a.z; r[3] = -2.f * acc[3] * dn - a.w;
            r[4] = -2.f * acc[4] * dn - b.x; r[5] = -2.f * acc[5] * dn - b.y;
            r[6] = -2.f * acc[6] * dn - b.z; r[7] = -2.f * acc[7] * dn - b.w;
        }
        float4 o0 = make_float4(r[0], r[1], r[2], r[3]);
        float4 o1 = make_float4(r[4], r[5], r[6], r[7]);
        *(float4*)(Xout + (size_t)node * NF + fl) = o0;
        *(float4*)(Xout + (size_t)node * NF + fl + 4) = o1;
    }
}

// ============ GEMM: 128 threads / 128 nodes per block; coalesced LDS-transposed epilogue ====
template <int OUTF>
__launch_bounds__(128)
__global__ void gemm_cheb(const float* __restrict__ X0, const float* __restrict__ X1,
                          const float* __restrict__ X2, const float* __restrict__ W,
                          const float* __restrict__ bias, float* __restrict__ out,
                          const float* __restrict__ dinv, u16* __restrict__ Yout,
                          int n, int do_relu) {
    __shared__ float xs[128 * 65];
    const int tid = threadIdx.x;
    const int node0 = blockIdx.x * 128;

    float acc[OUTF];
#pragma unroll
    for (int j = 0; j < OUTF; ++j) acc[j] = bias[j];

    const float* Xp[3] = {X0, X1, X2};
#pragma unroll 1
    for (int p = 0; p < 3; ++p) {
        const float* __restrict__ Xc = Xp[p];
#pragma unroll
        for (int j = 0; j < 16; ++j) {
            int idx4 = j * 128 + tid;
            int ln = idx4 >> 4;
            int k4 = (idx4 & 15) * 4;
            float4 v = make_float4(0.f, 0.f, 0.f, 0.f);
            int gnode = node0 + ln;
            if (gnode < n) v = *(const float4*)&Xc[(size_t)gnode * 64 + k4];
            float* s = &xs[ln * 65 + k4];
            s[0] = v.x; s[1] = v.y; s[2] = v.z; s[3] = v.w;
        }
        __syncthreads();

        const float* __restrict__ Wp = W + (size_t)p * 64 * OUTF;
        for (int k = 0; k < 64; ++k) {
            float x = xs[tid * 65 + k];
#pragma unroll
            for (int j = 0; j < OUTF; ++j)
                acc[j] += x * Wp[k * OUTF + j];
        }
        __syncthreads();
    }

    // epilogue: acc -> LDS (padded) -> coalesced global stores
    const int ST = OUTF + 1;
#pragma unroll
    for (int j = 0; j < OUTF; ++j) {
        float v = acc[j];
        if (do_relu) v = fmaxf(v, 0.f);
        xs[tid * ST + j] = v;
    }
    __syncthreads();

    if (OUTF == 64) {
#pragma unroll
        for (int j = 0; j < 16; ++j) {
            int idx4 = j * 128 + tid;
            int ln = idx4 >> 4;
            int k4 = (idx4 & 15) * 4;
            int gnode = node0 + ln;
            if (gnode < n) {
                const float* s = &xs[ln * 65 + k4];
                float4 v = make_float4(s[0], s[1], s[2], s[3]);
                *(float4*)&out[(size_t)gnode * 64 + k4] = v;
                if (Yout) {
                    float dn = dinv[gnode];
                    ushort4 y;
                    y.x = f2bf(v.x * dn); y.y = f2bf(v.y * dn);
                    y.z = f2bf(v.z * dn); y.w = f2bf(v.w * dn);
                    *(ushort4*)&Yout[(size_t)gnode * 64 + k4] = y;
                }
            }
        }
    } else {   // OUTF == 32
#pragma unroll
        for (int j = 0; j < 8; ++j) {
            int idx4 = j * 128 + tid;
            int ln = idx4 >> 3;
            int k4 = (idx4 & 7) * 4;
            int gnode = node0 + ln;
            if (gnode < n) {
                const float* s = &xs[ln * 33 + k4];
                *(float4*)&out[(size_t)gnode * 32 + k4] =
                    make_float4(s[0], s[1], s[2], s[3]);
            }
        }
    }
}

extern "C" void kernel_launch(void* const* d_in, const int* in_sizes, int n_in,
                              void* d_out, int out_size, void* d_ws, size_t ws_size,
                              hipStream_t stream) {
    const float* feat = (const float*)d_in[0];
    const int*   src  = (const int*)d_in[1];
    const int*   dst  = (const int*)d_in[2];
    const float* W1   = (const float*)d_in[3];
    const float* b1   = (const float*)d_in[4];
    const float* W2   = (const float*)d_in[5];
    const float* b2   = (const float*)d_in[6];
    float* out = (float*)d_out;

    const int N = in_sizes[0] / NF;   // 100000
    const int E = in_sizes[1];        // 1600000
    const size_t NFtot = (size_t)N * NF;
    const int n8 = N * NQ;            // 800000

    // workspace layout (16B-aligned chunks)
    char* p = (char*)d_ws;
    int* rowptr4  = (int*)p;        p += ((size_t)n8 + 16) * 4;
    int* csr_src  = (int*)p;        p += (size_t)E * 4;
    int* blocksum = (int*)p;        p += 1024 * 4;
    float* dinv   = (float*)p;      p += ((size_t)N + 16) * 4;
    float* X1     = (float*)p;      p += NFtot * 4;
    float* X2     = (float*)p;      p += NFtot * 4;
    float* H      = (float*)p;      p += NFtot * 4;
    u16* Ya       = (u16*)p;        p += NFtot * 2;   // Y0, later YH
    u16* Yb       = (u16*)p;        p += NFtot * 2;   // Y1 (both layers)
    int* cnt4 = (int*)X1;           // 3.2 MB alias; dead before X1 first written

    const int TB = 256;
    dim3 blk(TB);
    dim3 gE((E + TB - 1) / TB);
    const int nchunks = (E + TB - 1) / TB;            // 6250
    dim3 gFill(nchunks * FILL_PASSES);
    const int nb8 = (n8 + 1023) / 1024;               // 782
    dim3 gScan(nb8);
    dim3 gN((N + TB - 1) / TB);
    dim3 gWave(((size_t)N * 64 + TB - 1) / TB);
    dim3 gPre(((size_t)N * 16 + TB - 1) / TB);
    dim3 gGemm((N + 127) / 128);
    dim3 blk128(128);

    // ---- CSR build (slice-sorted) ----
    hipMemsetAsync(cnt4, 0, (size_t)n8 * sizeof(int), stream);
    count_kernel<<<gE, blk, 0, stream>>>(src, dst, cnt4, E);
    block_sums<<<gScan, blk, 0, stream>>>(cnt4, blocksum, n8);
    scan_blocksums<<<1, blk, 0, stream>>>(blocksum, rowptr4, nb8, n8, E);
    scan_finalize<<<gScan, blk, 0, stream>>>(cnt4, blocksum, rowptr4, n8);
    dinv_kernel<<<gN, blk, 0, stream>>>(rowptr4, dinv, N);
    fill_kernel<<<gFill, blk, 0, stream>>>(src, dst, rowptr4, cnt4, csr_src, E, N, nchunks);

    // ---- layer 1 ----
    prescale<<<gPre, blk, 0, stream>>>(feat, dinv, Ya, (int)(N * 16));
    spmm_bf16<<<gWave, blk, 0, stream>>>(Ya, rowptr4, csr_src, dinv, nullptr, X1, Yb, N, 1);
    spmm_bf16<<<gWave, blk, 0, stream>>>(Yb, rowptr4, csr_src, dinv, feat, X2, nullptr, N, 2);
    gemm_cheb<64><<<gGemm, blk128, 0, stream>>>(feat, X1, X2, W1, b1, H, dinv, Ya, N, 1);

    // ---- layer 2 ----
    spmm_bf16<<<gWave, blk, 0, stream>>>(Ya, rowptr4, csr_src, dinv, nullptr, X1, Yb, N, 1);
    spmm_bf16<<<gWave, blk, 0, stream>>>(Yb, rowptr4, csr_src, dinv, H, X2, nullptr, N, 2);
    gemm_cheb<32><<<gGemm, blk128, 0, stream>>>(H, X1, X2, W2, b2, out, dinv, nullptr, N, 0);
}

// Round 8
// 616.462 us; speedup vs baseline: 1.2713x; 1.2713x over previous
//
#include <hip/hip_runtime.h>

#define NF 64   // IN_F == HID_F == 64
#define FILL_PASSES 8

typedef unsigned short u16;

__device__ __forceinline__ float bf2f(unsigned h) {
    return __uint_as_float(h << 16);
}
__device__ __forceinline__ u16 f2bf(float x) {   // round-to-nearest-even
    unsigned u = __float_as_uint(x);
    return (u16)((u + 0x7FFFu + ((u >> 16) & 1u)) >> 16);
}

// ============ CSR build (counting sort by dst) — round-6 proven version ============

__global__ void count_kernel(const int* __restrict__ dst, int* __restrict__ cnt, int E) {
    int e = blockIdx.x * blockDim.x + threadIdx.x;
    if (e < E) atomicAdd(&cnt[dst[e]], 1);
}

__global__ void block_sums(const int* __restrict__ cnt, int* __restrict__ blocksum, int n) {
    int tid = threadIdx.x;
    int base_i = blockIdx.x * 1024 + tid * 4;
    int t = 0;
#pragma unroll
    for (int j = 0; j < 4; ++j) t += (base_i + j < n) ? cnt[base_i + j] : 0;
    __shared__ int s[256];
    s[tid] = t; __syncthreads();
    for (int off = 128; off > 0; off >>= 1) {
        if (tid < off) s[tid] += s[tid + off];
        __syncthreads();
    }
    if (tid == 0) blocksum[blockIdx.x] = s[0];
}

__global__ void scan_blocksums(int* __restrict__ blocksum, int* __restrict__ rowptr,
                               int nb, int n) {
    int tid = threadIdx.x;
    int v = (tid < nb) ? blocksum[tid] : 0;
    __shared__ int s[256];
    s[tid] = v; __syncthreads();
    for (int off = 1; off < 256; off <<= 1) {
        int t = (tid >= off) ? s[tid - off] : 0;
        __syncthreads();
        s[tid] += t;
        __syncthreads();
    }
    if (tid < nb) blocksum[tid] = s[tid] - v;   // exclusive
    if (tid == 255) rowptr[n] = s[255];         // total == E
}

__global__ void scan_finalize(int* __restrict__ cnt, const int* __restrict__ blocksum,
                              int* __restrict__ rowptr, float* __restrict__ dinv, int n) {
    int tid = threadIdx.x;
    int base_i = blockIdx.x * 1024 + tid * 4;
    int v[4]; int tsum = 0;
#pragma unroll
    for (int j = 0; j < 4; ++j) { v[j] = (base_i + j < n) ? cnt[base_i + j] : 0; tsum += v[j]; }
    __shared__ int s[256];
    s[tid] = tsum; __syncthreads();
    for (int off = 1; off < 256; off <<= 1) {
        int t = (tid >= off) ? s[tid - off] : 0;
        __syncthreads();
        s[tid] += t;
        __syncthreads();
    }
    int base = blocksum[blockIdx.x] + (s[tid] - tsum);
#pragma unroll
    for (int j = 0; j < 4; ++j) {
        int i = base_i + j;
        if (i < n) {
            rowptr[i] = base;
            dinv[i] = rsqrtf(fmaxf((float)v[j], 1.0f));
            cnt[i] = 0;       // reused as cursor by fill_kernel
            base += v[j];
        }
    }
}

// multi-pass fill: pass p (from blockIdx) handles dst in [N*p/P, N*(p+1)/P)
__global__ void fill_kernel(const int* __restrict__ src, const int* __restrict__ dst,
                            const int* __restrict__ rowptr, int* __restrict__ cursor,
                            int* __restrict__ csr_src, int E, int N, int nchunks) {
    int b = blockIdx.x;
    int pass = b / nchunks;
    int chunk = b - pass * nchunks;
    int e = chunk * 256 + threadIdx.x;
    if (e >= E) return;
    int lo = (int)(((long long)N * pass) / FILL_PASSES);
    int hi = (int)(((long long)N * (pass + 1)) / FILL_PASSES);
    int d = dst[e];
    if (d >= lo && d < hi) {
        int pos = rowptr[d] + atomicAdd(&cursor[d], 1);
        csr_src[pos] = src[e];
    }
}

// ============ prescale: Y = bf16(X * dinv[node]) ============
__global__ void prescale(const float* __restrict__ X, const float* __restrict__ dinv,
                         u16* __restrict__ Y, int total4) {   // total4 = N*16
    int i = blockIdx.x * blockDim.x + threadIdx.x;
    if (i < total4) {
        int node = i >> 4;
        float dn = dinv[node];
        float4 v = ((const float4*)X)[i];
        ushort4 y;
        y.x = f2bf(v.x * dn); y.y = f2bf(v.y * dn);
        y.z = f2bf(v.z * dn); y.w = f2bf(v.w * dn);
        ((ushort4*)Y)[i] = y;
    }
}

// ============ SpMM gather (bf16 rows): wave/node, 8 edges/iter, 16B loads ============
__launch_bounds__(256)
__global__ void spmm_bf16(const u16* __restrict__ Y, const int* __restrict__ rowptr,
                          const int* __restrict__ csr_src, const float* __restrict__ dinv,
                          const float* __restrict__ Xprev, float* __restrict__ Xout,
                          u16* __restrict__ Yout, int n, int mode) {
    int node = (blockIdx.x * blockDim.x + threadIdx.x) >> 6;
    if (node >= n) return;
    int lane = threadIdx.x & 63;
    int g = lane >> 3;            // edge subgroup 0..7
    int fl = (lane & 7) << 3;     // feature offset 0,8,...,56

    int beg = rowptr[node], end = rowptr[node + 1];
    float acc[8];
#pragma unroll
    for (int j = 0; j < 8; ++j) acc[j] = 0.f;

    for (int e0 = beg; e0 < end; e0 += 8) {
        int eg = e0 + g;
        if (eg < end) {
            int s = csr_src[eg];
            uint4 u = *(const uint4*)(Y + (size_t)s * NF + fl);
            acc[0] += bf2f(u.x & 0xFFFFu); acc[1] += bf2f(u.x >> 16);
            acc[2] += bf2f(u.y & 0xFFFFu); acc[3] += bf2f(u.y >> 16);
            acc[4] += bf2f(u.z & 0xFFFFu); acc[5] += bf2f(u.z >> 16);
            acc[6] += bf2f(u.w & 0xFFFFu); acc[7] += bf2f(u.w >> 16);
        }
    }
#pragma unroll
    for (int m = 8; m <= 32; m <<= 1) {
#pragma unroll
        for (int j = 0; j < 8; ++j) acc[j] += __shfl_xor(acc[j], m, 64);
    }
    if (g == 0) {
        float dn = dinv[node];
        float r[8];
        if (mode == 1) {
#pragma unroll
            for (int j = 0; j < 8; ++j) r[j] = -acc[j] * dn;
            uint4 uy;
            uy.x = (unsigned)f2bf(r[0] * dn) | ((unsigned)f2bf(r[1] * dn) << 16);
            uy.y = (unsigned)f2bf(r[2] * dn) | ((unsigned)f2bf(r[3] * dn) << 16);
            uy.z = (unsigned)f2bf(r[4] * dn) | ((unsigned)f2bf(r[5] * dn) << 16);
            uy.w = (unsigned)f2bf(r[6] * dn) | ((unsigned)f2bf(r[7] * dn) << 16);
            *(uint4*)(Yout + (size_t)node * NF + fl) = uy;
        } else {
            float4 a = *(const float4*)(Xprev + (size_t)node * NF + fl);
            float4 b = *(const float4*)(Xprev + (size_t)node * NF + fl + 4);
            r[0] = -2.f * acc[0] * dn - a.x; r[1] = -2.f * acc[1] * dn - a.y;
            r[2] = -2.f * acc[2] * dn - a.z; r[3] = -2.f * acc[3] * dn - a.w;
            r[4] = -2.f * acc[4] * dn - b.x; r[5] = -2.f * acc[5] * dn - b.y;
            r[6] = -2.f * acc[6] * dn - b.z; r[7] = -2.f * acc[7] * dn - b.w;
        }
        float4 o0 = make_float4(r[0], r[1], r[2], r[3]);
        float4 o1 = make_float4(r[4], r[5], r[6], r[7]);
        *(float4*)(Xout + (size_t)node * NF + fl) = o0;
        *(float4*)(Xout + (size_t)node * NF + fl + 4) = o1;
    }
}

// ============ GEMM: 128 nodes/block, K split in 32-wide stages ============
// LDS = 128*33 floats = 16.9 KB -> ~9 blocks/CU (vs 4 with the 65-wide tile).
// Epilogue runs in 32-out halves through the same buffer: a 32-float half-row
// is 128 B = 2 full cache lines, so stores stay fully coalesced.
template <int OUTF>
__launch_bounds__(128)
__global__ void gemm_cheb(const float* __restrict__ X0, const float* __restrict__ X1,
                          const float* __restrict__ X2, const float* __restrict__ W,
                          const float* __restrict__ bias, float* __restrict__ out,
                          const float* __restrict__ dinv, u16* __restrict__ Yout,
                          int n, int do_relu) {
    __shared__ float xs[128 * 33];
    const int tid = threadIdx.x;
    const int node0 = blockIdx.x * 128;

    float acc[OUTF];
#pragma unroll
    for (int j = 0; j < OUTF; ++j) acc[j] = bias[j];

    const float* Xp[3] = {X0, X1, X2};
#pragma unroll 1
    for (int p = 0; p < 3; ++p) {
        const float* __restrict__ Xc = Xp[p];
#pragma unroll 1
        for (int h = 0; h < 2; ++h) {
            // stage 128 node-rows × 32 floats: 1024 float4 / 128 threads = 8 iters
#pragma unroll
            for (int it = 0; it < 8; ++it) {
                int idx4 = it * 128 + tid;
                int ln = idx4 >> 3;
                int k4 = (idx4 & 7) * 4;
                float4 v = make_float4(0.f, 0.f, 0.f, 0.f);
                int gnode = node0 + ln;
                if (gnode < n) v = *(const float4*)&Xc[(size_t)gnode * 64 + h * 32 + k4];
                float* s = &xs[ln * 33 + k4];
                s[0] = v.x; s[1] = v.y; s[2] = v.z; s[3] = v.w;
            }
            __syncthreads();

            const float* __restrict__ Wp = W + (size_t)p * 64 * OUTF + (size_t)h * 32 * OUTF;
            for (int k = 0; k < 32; ++k) {
                float x = xs[tid * 33 + k];
#pragma unroll
                for (int j = 0; j < OUTF; ++j)
                    acc[j] += x * Wp[k * OUTF + j];
            }
            __syncthreads();
        }
    }

    // ---- epilogue: LDS-transposed, in 32-out halves ----
    if (OUTF == 64) {
#pragma unroll 1
        for (int h = 0; h < 2; ++h) {
#pragma unroll
            for (int j = 0; j < 32; ++j) {
                float v = acc[h * 32 + j];
                if (do_relu) v = fmaxf(v, 0.f);
                xs[tid * 33 + j] = v;
            }
            __syncthreads();
#pragma unroll
            for (int it = 0; it < 8; ++it) {
                int idx4 = it * 128 + tid;
                int ln = idx4 >> 3;
                int k4 = (idx4 & 7) * 4;
                int gnode = node0 + ln;
                if (gnode < n) {
                    const float* s = &xs[ln * 33 + k4];
                    float4 v = make_float4(s[0], s[1], s[2], s[3]);
                    *(float4*)&out[(size_t)gnode * 64 + h * 32 + k4] = v;
                    if (Yout) {
                        float dn = dinv[gnode];
                        ushort4 y;
                        y.x = f2bf(v.x * dn); y.y = f2bf(v.y * dn);
                        y.z = f2bf(v.z * dn); y.w = f2bf(v.w * dn);
                        *(ushort4*)&Yout[(size_t)gnode * 64 + h * 32 + k4] = y;
                    }
                }
            }
            __syncthreads();
        }
    } else {   // OUTF == 32: single pass
#pragma unroll
        for (int j = 0; j < 32; ++j) {
            float v = acc[j];
            if (do_relu) v = fmaxf(v, 0.f);
            xs[tid * 33 + j] = v;
        }
        __syncthreads();
#pragma unroll
        for (int it = 0; it < 8; ++it) {
            int idx4 = it * 128 + tid;
            int ln = idx4 >> 3;
            int k4 = (idx4 & 7) * 4;
            int gnode = node0 + ln;
            if (gnode < n) {
                const float* s = &xs[ln * 33 + k4];
                *(float4*)&out[(size_t)gnode * 32 + k4] =
                    make_float4(s[0], s[1], s[2], s[3]);
            }
        }
    }
}

extern "C" void kernel_launch(void* const* d_in, const int* in_sizes, int n_in,
                              void* d_out, int out_size, void* d_ws, size_t ws_size,
                              hipStream_t stream) {
    const float* feat = (const float*)d_in[0];
    const int*   src  = (const int*)d_in[1];
    const int*   dst  = (const int*)d_in[2];
    const float* W1   = (const float*)d_in[3];
    const float* b1   = (const float*)d_in[4];
    const float* W2   = (const float*)d_in[5];
    const float* b2   = (const float*)d_in[6];
    float* out = (float*)d_out;

    const int N = in_sizes[0] / NF;   // 100000
    const int E = in_sizes[1];        // 1600000
    const size_t NFtot = (size_t)N * NF;

    // workspace layout (all chunks 16B-aligned)
    char* p = (char*)d_ws;
    int* cnt      = (int*)p;        p += ((size_t)N + 256) * 4;
    int* rowptr   = (int*)p;        p += ((size_t)N + 256) * 4;
    int* csr_src  = (int*)p;        p += (size_t)E * 4;
    int* blocksum = (int*)p;        p += 256 * 4;
    float* dinv   = (float*)p;      p += ((size_t)N + 256) * 4;
    float* X1     = (float*)p;      p += NFtot * 4;
    float* X2     = (float*)p;      p += NFtot * 4;
    float* H      = (float*)p;      p += NFtot * 4;
    u16* Ya       = (u16*)p;        p += NFtot * 2;   // Y0, later YH
    u16* Yb       = (u16*)p;        p += NFtot * 2;   // Y1 (both layers)

    const int TB = 256;
    dim3 blk(TB);
    dim3 gE((E + TB - 1) / TB);
    const int nchunks = (E + TB - 1) / TB;            // 6250
    dim3 gFill(nchunks * FILL_PASSES);
    const int nb = (N + 1023) / 1024;   // 98 (must be <=256)
    dim3 gScan(nb);
    dim3 gWave(((size_t)N * 64 + TB - 1) / TB);
    dim3 gPre(((size_t)N * 16 + TB - 1) / TB);
    dim3 gGemm((N + 127) / 128);
    dim3 blk128(128);

    // ---- CSR build ----
    hipMemsetAsync(cnt, 0, (size_t)N * sizeof(int), stream);
    count_kernel<<<gE, blk, 0, stream>>>(dst, cnt, E);
    block_sums<<<gScan, blk, 0, stream>>>(cnt, blocksum, N);
    scan_blocksums<<<1, blk, 0, stream>>>(blocksum, rowptr, nb, N);
    scan_finalize<<<gScan, blk, 0, stream>>>(cnt, blocksum, rowptr, dinv, N);
    fill_kernel<<<gFill, blk, 0, stream>>>(src, dst, rowptr, cnt, csr_src, E, N, nchunks);

    // ---- layer 1 ----
    prescale<<<gPre, blk, 0, stream>>>(feat, dinv, Ya, (int)(N * 16));
    spmm_bf16<<<gWave, blk, 0, stream>>>(Ya, rowptr, csr_src, dinv, nullptr, X1, Yb, N, 1);
    spmm_bf16<<<gWave, blk, 0, stream>>>(Yb, rowptr, csr_src, dinv, feat, X2, nullptr, N, 2);
    gemm_cheb<64><<<gGemm, blk128, 0, stream>>>(feat, X1, X2, W1, b1, H, dinv, Ya, N, 1);

    // ---- layer 2 ----
    spmm_bf16<<<gWave, blk, 0, stream>>>(Ya, rowptr, csr_src, dinv, nullptr, X1, Yb, N, 1);
    spmm_bf16<<<gWave, blk, 0, stream>>>(Yb, rowptr, csr_src, dinv, H, X2, nullptr, N, 2);
    gemm_cheb<32><<<gGemm, blk128, 0, stream>>>(H, X1, X2, W2, b2, out, dinv, nullptr, N, 0);
}

// Round 9
// 511.810 us; speedup vs baseline: 1.5313x; 1.2045x over previous
//
#include <hip/hip_runtime.h>

#define NF 64   // IN_F == HID_F == 64
#define FILL_PASSES 8

typedef unsigned short u16;

__device__ __forceinline__ float bf2f(unsigned h) {
    return __uint_as_float(h << 16);
}
__device__ __forceinline__ u16 f2bf(float x) {   // round-to-nearest-even
    unsigned u = __float_as_uint(x);
    return (u16)((u + 0x7FFFu + ((u >> 16) & 1u)) >> 16);
}

// ============ CSR build (counting sort by dst) — round-6 proven version ============

__global__ void count_kernel(const int* __restrict__ dst, int* __restrict__ cnt, int E) {
    int e = blockIdx.x * blockDim.x + threadIdx.x;
    if (e < E) atomicAdd(&cnt[dst[e]], 1);
}

__global__ void block_sums(const int* __restrict__ cnt, int* __restrict__ blocksum, int n) {
    int tid = threadIdx.x;
    int base_i = blockIdx.x * 1024 + tid * 4;
    int t = 0;
#pragma unroll
    for (int j = 0; j < 4; ++j) t += (base_i + j < n) ? cnt[base_i + j] : 0;
    __shared__ int s[256];
    s[tid] = t; __syncthreads();
    for (int off = 128; off > 0; off >>= 1) {
        if (tid < off) s[tid] += s[tid + off];
        __syncthreads();
    }
    if (tid == 0) blocksum[blockIdx.x] = s[0];
}

__global__ void scan_blocksums(int* __restrict__ blocksum, int* __restrict__ rowptr,
                               int nb, int n) {
    int tid = threadIdx.x;
    int v = (tid < nb) ? blocksum[tid] : 0;
    __shared__ int s[256];
    s[tid] = v; __syncthreads();
    for (int off = 1; off < 256; off <<= 1) {
        int t = (tid >= off) ? s[tid - off] : 0;
        __syncthreads();
        s[tid] += t;
        __syncthreads();
    }
    if (tid < nb) blocksum[tid] = s[tid] - v;   // exclusive
    if (tid == 255) rowptr[n] = s[255];         // total == E
}

__global__ void scan_finalize(int* __restrict__ cnt, const int* __restrict__ blocksum,
                              int* __restrict__ rowptr, float* __restrict__ dinv, int n) {
    int tid = threadIdx.x;
    int base_i = blockIdx.x * 1024 + tid * 4;
    int v[4]; int tsum = 0;
#pragma unroll
    for (int j = 0; j < 4; ++j) { v[j] = (base_i + j < n) ? cnt[base_i + j] : 0; tsum += v[j]; }
    __shared__ int s[256];
    s[tid] = tsum; __syncthreads();
    for (int off = 1; off < 256; off <<= 1) {
        int t = (tid >= off) ? s[tid - off] : 0;
        __syncthreads();
        s[tid] += t;
        __syncthreads();
    }
    int base = blocksum[blockIdx.x] + (s[tid] - tsum);
#pragma unroll
    for (int j = 0; j < 4; ++j) {
        int i = base_i + j;
        if (i < n) {
            rowptr[i] = base;
            dinv[i] = rsqrtf(fmaxf((float)v[j], 1.0f));
            cnt[i] = 0;       // reused as cursor by fill_kernel
            base += v[j];
        }
    }
}

// multi-pass fill: pass p (from blockIdx) handles dst in [N*p/P, N*(p+1)/P)
__global__ void fill_kernel(const int* __restrict__ src, const int* __restrict__ dst,
                            const int* __restrict__ rowptr, int* __restrict__ cursor,
                            int* __restrict__ csr_src, int E, int N, int nchunks) {
    int b = blockIdx.x;
    int pass = b / nchunks;
    int chunk = b - pass * nchunks;
    int e = chunk * 256 + threadIdx.x;
    if (e >= E) return;
    int lo = (int)(((long long)N * pass) / FILL_PASSES);
    int hi = (int)(((long long)N * (pass + 1)) / FILL_PASSES);
    int d = dst[e];
    if (d >= lo && d < hi) {
        int pos = rowptr[d] + atomicAdd(&cursor[d], 1);
        csr_src[pos] = src[e];
    }
}

// ============ prescale: Y = bf16(X * dinv[node]) ============
__global__ void prescale(const float* __restrict__ X, const float* __restrict__ dinv,
                         u16* __restrict__ Y, int total4) {   // total4 = N*16
    int i = blockIdx.x * blockDim.x + threadIdx.x;
    if (i < total4) {
        int node = i >> 4;
        float dn = dinv[node];
        float4 v = ((const float4*)X)[i];
        ushort4 y;
        y.x = f2bf(v.x * dn); y.y = f2bf(v.y * dn);
        y.z = f2bf(v.z * dn); y.w = f2bf(v.w * dn);
        ((ushort4*)Y)[i] = y;
    }
}

// ============ SpMM gather (bf16 rows): wave/node, 8 edges/iter, 16B loads ============
__launch_bounds__(256)
__global__ void spmm_bf16(const u16* __restrict__ Y, const int* __restrict__ rowptr,
                          const int* __restrict__ csr_src, const float* __restrict__ dinv,
                          const float* __restrict__ Xprev, float* __restrict__ Xout,
                          u16* __restrict__ Yout, int n, int mode) {
    int node = (blockIdx.x * blockDim.x + threadIdx.x) >> 6;
    if (node >= n) return;
    int lane = threadIdx.x & 63;
    int g = lane >> 3;            // edge subgroup 0..7
    int fl = (lane & 7) << 3;     // feature offset 0,8,...,56

    int beg = rowptr[node], end = rowptr[node + 1];
    float acc[8];
#pragma unroll
    for (int j = 0; j < 8; ++j) acc[j] = 0.f;

    for (int e0 = beg; e0 < end; e0 += 8) {
        int eg = e0 + g;
        if (eg < end) {
            int s = csr_src[eg];
            uint4 u = *(const uint4*)(Y + (size_t)s * NF + fl);
            acc[0] += bf2f(u.x & 0xFFFFu); acc[1] += bf2f(u.x >> 16);
            acc[2] += bf2f(u.y & 0xFFFFu); acc[3] += bf2f(u.y >> 16);
            acc[4] += bf2f(u.z & 0xFFFFu); acc[5] += bf2f(u.z >> 16);
            acc[6] += bf2f(u.w & 0xFFFFu); acc[7] += bf2f(u.w >> 16);
        }
    }
#pragma unroll
    for (int m = 8; m <= 32; m <<= 1) {
#pragma unroll
        for (int j = 0; j < 8; ++j) acc[j] += __shfl_xor(acc[j], m, 64);
    }
    if (g == 0) {
        float dn = dinv[node];
        float r[8];
        if (mode == 1) {
#pragma unroll
            for (int j = 0; j < 8; ++j) r[j] = -acc[j] * dn;
            uint4 uy;
            uy.x = (unsigned)f2bf(r[0] * dn) | ((unsigned)f2bf(r[1] * dn) << 16);
            uy.y = (unsigned)f2bf(r[2] * dn) | ((unsigned)f2bf(r[3] * dn) << 16);
            uy.z = (unsigned)f2bf(r[4] * dn) | ((unsigned)f2bf(r[5] * dn) << 16);
            uy.w = (unsigned)f2bf(r[6] * dn) | ((unsigned)f2bf(r[7] * dn) << 16);
            *(uint4*)(Yout + (size_t)node * NF + fl) = uy;
        } else {
            float4 a = *(const float4*)(Xprev + (size_t)node * NF + fl);
            float4 b = *(const float4*)(Xprev + (size_t)node * NF + fl + 4);
            r[0] = -2.f * acc[0] * dn - a.x; r[1] = -2.f * acc[1] * dn - a.y;
            r[2] = -2.f * acc[2] * dn - a.z; r[3] = -2.f * acc[3] * dn - a.w;
            r[4] = -2.f * acc[4] * dn - b.x; r[5] = -2.f * acc[5] * dn - b.y;
            r[6] = -2.f * acc[6] * dn - b.z; r[7] = -2.f * acc[7] * dn - b.w;
        }
        float4 o0 = make_float4(r[0], r[1], r[2], r[3]);
        float4 o1 = make_float4(r[4], r[5], r[6], r[7]);
        *(float4*)(Xout + (size_t)node * NF + fl) = o0;
        *(float4*)(Xout + (size_t)node * NF + fl + 4) = o1;
    }
}

// ============ GEMM v3: 256 threads / 128 nodes; OUTF split across wave-pairs ============
// thread t: node = t&127, out-half ho = t>>7 (wave-uniform -> W stays s_load).
// acc[OUTF/2] only; K staged in 32-wide tiles (LDS 128*33 = 16.9 KB).
// All acc[] indices are compile-time constants (NO dynamic indexing -> no spill).
template <int OUTF>
__launch_bounds__(256)
__global__ void gemm_cheb(const float* __restrict__ X0, const float* __restrict__ X1,
                          const float* __restrict__ X2, const float* __restrict__ W,
                          const float* __restrict__ bias, float* __restrict__ out,
                          const float* __restrict__ dinv, u16* __restrict__ Yout,
                          int n, int do_relu) {
    constexpr int HALF = OUTF / 2;     // 32 or 16
    constexpr int EST = HALF + 1;      // epilogue LDS stride
    __shared__ float xs[128 * 33];
    const int tid = threadIdx.x;
    const int node0 = blockIdx.x * 128;
    const int ln = tid & 127;
    const int ho_u = __builtin_amdgcn_readfirstlane(tid >> 7);  // wave-uniform half idx

    float acc[HALF];
#pragma unroll
    for (int j = 0; j < HALF; ++j) acc[j] = bias[ho_u * HALF + j];

    const float* Xp[3] = {X0, X1, X2};
#pragma unroll 1
    for (int p = 0; p < 3; ++p) {
        const float* __restrict__ Xc = Xp[p];
#pragma unroll 1
        for (int h = 0; h < 2; ++h) {
            // stage 128 rows × 32 floats = 1024 float4; 256 threads -> 4 iters
#pragma unroll
            for (int it = 0; it < 4; ++it) {
                int idx4 = it * 256 + tid;
                int ln2 = idx4 >> 3;
                int k4 = (idx4 & 7) * 4;
                float4 v = make_float4(0.f, 0.f, 0.f, 0.f);
                int gnode = node0 + ln2;
                if (gnode < n) v = *(const float4*)&Xc[(size_t)gnode * 64 + h * 32 + k4];
                float* s = &xs[ln2 * 33 + k4];
                s[0] = v.x; s[1] = v.y; s[2] = v.z; s[3] = v.w;
            }
            __syncthreads();

            const float* __restrict__ Wp =
                W + (size_t)p * 64 * OUTF + (size_t)h * 32 * OUTF + ho_u * HALF;
            for (int k = 0; k < 32; ++k) {
                float x = xs[ln * 33 + k];
#pragma unroll
                for (int j = 0; j < HALF; ++j)
                    acc[j] += x * Wp[k * OUTF + j];
            }
            __syncthreads();
        }
    }

    // ---- epilogue: two phases (hp = 0,1), all indices compile-time ----
#pragma unroll 1
    for (int hp = 0; hp < 2; ++hp) {
        if (ho_u == hp) {
#pragma unroll
            for (int j = 0; j < HALF; ++j) {
                float v = acc[j];
                if (do_relu) v = fmaxf(v, 0.f);
                xs[ln * EST + j] = v;
            }
        }
        __syncthreads();
        // write 128 rows × HALF floats, fully coalesced
        constexpr int NIT = (128 * HALF / 4) / 256;   // 4 (OUTF=64) or 2 (OUTF=32)
#pragma unroll
        for (int it = 0; it < NIT; ++it) {
            int idx4 = it * 256 + tid;
            int ln2 = idx4 / (HALF / 4);
            int k4 = (idx4 % (HALF / 4)) * 4;
            int gnode = node0 + ln2;
            if (gnode < n) {
                const float* s = &xs[ln2 * EST + k4];
                float4 v = make_float4(s[0], s[1], s[2], s[3]);
                *(float4*)&out[(size_t)gnode * OUTF + hp * HALF + k4] = v;
                if (OUTF == 64 && Yout) {
                    float dn = dinv[gnode];
                    ushort4 y;
                    y.x = f2bf(v.x * dn); y.y = f2bf(v.y * dn);
                    y.z = f2bf(v.z * dn); y.w = f2bf(v.w * dn);
                    *(ushort4*)&Yout[(size_t)gnode * OUTF + hp * HALF + k4] = y;
                }
            }
        }
        __syncthreads();
    }
}

extern "C" void kernel_launch(void* const* d_in, const int* in_sizes, int n_in,
                              void* d_out, int out_size, void* d_ws, size_t ws_size,
                              hipStream_t stream) {
    const float* feat = (const float*)d_in[0];
    const int*   src  = (const int*)d_in[1];
    const int*   dst  = (const int*)d_in[2];
    const float* W1   = (const float*)d_in[3];
    const float* b1   = (const float*)d_in[4];
    const float* W2   = (const float*)d_in[5];
    const float* b2   = (const float*)d_in[6];
    float* out = (float*)d_out;

    const int N = in_sizes[0] / NF;   // 100000
    const int E = in_sizes[1];        // 1600000
    const size_t NFtot = (size_t)N * NF;

    // workspace layout (all chunks 16B-aligned)
    char* p = (char*)d_ws;
    int* cnt      = (int*)p;        p += ((size_t)N + 256) * 4;
    int* rowptr   = (int*)p;        p += ((size_t)N + 256) * 4;
    int* csr_src  = (int*)p;        p += (size_t)E * 4;
    int* blocksum = (int*)p;        p += 256 * 4;
    float* dinv   = (float*)p;      p += ((size_t)N + 256) * 4;
    float* X1     = (float*)p;      p += NFtot * 4;
    float* X2     = (float*)p;      p += NFtot * 4;
    float* H      = (float*)p;      p += NFtot * 4;
    u16* Ya       = (u16*)p;        p += NFtot * 2;   // Y0, later YH
    u16* Yb       = (u16*)p;        p += NFtot * 2;   // Y1 (both layers)

    const int TB = 256;
    dim3 blk(TB);
    dim3 gE((E + TB - 1) / TB);
    const int nchunks = (E + TB - 1) / TB;            // 6250
    dim3 gFill(nchunks * FILL_PASSES);
    const int nb = (N + 1023) / 1024;   // 98 (must be <=256)
    dim3 gScan(nb);
    dim3 gWave(((size_t)N * 64 + TB - 1) / TB);
    dim3 gPre(((size_t)N * 16 + TB - 1) / TB);
    dim3 gGemm((N + 127) / 128);

    // ---- CSR build ----
    hipMemsetAsync(cnt, 0, (size_t)N * sizeof(int), stream);
    count_kernel<<<gE, blk, 0, stream>>>(dst, cnt, E);
    block_sums<<<gScan, blk, 0, stream>>>(cnt, blocksum, N);
    scan_blocksums<<<1, blk, 0, stream>>>(blocksum, rowptr, nb, N);
    scan_finalize<<<gScan, blk, 0, stream>>>(cnt, blocksum, rowptr, dinv, N);
    fill_kernel<<<gFill, blk, 0, stream>>>(src, dst, rowptr, cnt, csr_src, E, N, nchunks);

    // ---- layer 1 ----
    prescale<<<gPre, blk, 0, stream>>>(feat, dinv, Ya, (int)(N * 16));
    spmm_bf16<<<gWave, blk, 0, stream>>>(Ya, rowptr, csr_src, dinv, nullptr, X1, Yb, N, 1);
    spmm_bf16<<<gWave, blk, 0, stream>>>(Yb, rowptr, csr_src, dinv, feat, X2, nullptr, N, 2);
    gemm_cheb<64><<<gGemm, blk, 0, stream>>>(feat, X1, X2, W1, b1, H, dinv, Ya, N, 1);

    // ---- layer 2 ----
    spmm_bf16<<<gWave, blk, 0, stream>>>(Ya, rowptr, csr_src, dinv, nullptr, X1, Yb, N, 1);
    spmm_bf16<<<gWave, blk, 0, stream>>>(Yb, rowptr, csr_src, dinv, H, X2, nullptr, N, 2);
    gemm_cheb<32><<<gGemm, blk, 0, stream>>>(H, X1, X2, W2, b2, out, dinv, nullptr, N, 0);
}

// Round 10
// 417.333 us; speedup vs baseline: 1.8779x; 1.2264x over previous
//
#include <hip/hip_runtime.h>

#define NF 64        // IN_F == HID_F == 64
#define BKSH 9       // bucket = dst >> 9 (512 nodes/bucket)
#define BKN 512      // nodes per bucket
#define SB 256       // superblocks (edge partitions)

typedef unsigned short u16;

__device__ __forceinline__ float bf2f(unsigned h) {
    return __uint_as_float(h << 16);
}
__device__ __forceinline__ u16 f2bf(float x) {   // round-to-nearest-even
    unsigned u = __float_as_uint(x);
    return (u16)((u + 0x7FFFu + ((u >> 16) & 1u)) >> 16);
}

// ============ CSR build: two-phase radix partition, block-private windows ============

// phase A: per-superblock LDS histogram over buckets; hist is bucket-major:
// hist[b * SB + sb]. Also atomic bucket totals (196 addrs, no-return).
__launch_bounds__(256)
__global__ void radix_count(const int* __restrict__ dst, int* __restrict__ hist,
                            int* __restrict__ bucket_total, int E, int epb, int nbuk) {
    __shared__ int bins[BKN];
    int tid = threadIdx.x, sb = blockIdx.x;
    for (int i = tid; i < nbuk; i += 256) bins[i] = 0;
    __syncthreads();
    int base = sb * epb;
    int end = min(base + epb, E);
    for (int e = base + tid; e < end; e += 256)
        atomicAdd(&bins[dst[e] >> BKSH], 1);
    __syncthreads();
    for (int i = tid; i < nbuk; i += 256) {
        int c = bins[i];
        hist[i * SB + sb] = c;
        if (c) atomicAdd(&bucket_total[i], c);
    }
}

// phase B1: single block, exclusive scan of nbuk (<=256) bucket totals
__global__ void bucket_scan(const int* __restrict__ bucket_total, int* __restrict__ bucket_base,
                            int* __restrict__ rowptr, int nbuk, int E, int N) {
    __shared__ int s[256];
    int tid = threadIdx.x;
    int v = (tid < nbuk) ? bucket_total[tid] : 0;
    s[tid] = v; __syncthreads();
    for (int off = 1; off < 256; off <<= 1) {
        int t = (tid >= off) ? s[tid - off] : 0;
        __syncthreads();
        s[tid] += t;
        __syncthreads();
    }
    if (tid <= nbuk) bucket_base[tid] = (tid < nbuk) ? (s[tid] - v) : E;
    if (tid == 0) rowptr[N] = E;
}

// phase B2: one block per bucket: exclusive scan of its SB counts -> window offsets
__global__ void hist_scan(int* __restrict__ hist, const int* __restrict__ bucket_base) {
    __shared__ int s[256];
    int b = blockIdx.x, tid = threadIdx.x;
    int v = hist[b * SB + tid];
    s[tid] = v; __syncthreads();
    for (int off = 1; off < 256; off <<= 1) {
        int t = (tid >= off) ? s[tid - off] : 0;
        __syncthreads();
        s[tid] += t;
        __syncthreads();
    }
    hist[b * SB + tid] = bucket_base[b] + s[tid] - v;
}

// phase C: scatter packed (dlow<<17 | src) into block-private windows (LDS cursors)
__launch_bounds__(256)
__global__ void radix_scatter(const int* __restrict__ src, const int* __restrict__ dst,
                              const int* __restrict__ hist, int* __restrict__ tmp,
                              int E, int epb, int nbuk) {
    __shared__ int cur[BKN];
    int tid = threadIdx.x, sb = blockIdx.x;
    for (int i = tid; i < nbuk; i += 256) cur[i] = hist[i * SB + sb];
    __syncthreads();
    int base = sb * epb;
    int end = min(base + epb, E);
    for (int e = base + tid; e < end; e += 256) {
        int d = dst[e];
        int b = d >> BKSH;
        int pos = atomicAdd(&cur[b], 1);
        tmp[pos] = ((d & (BKN - 1)) << 17) | src[e];
    }
}

// phase D: one block per bucket: 512-bin LDS counting sort -> rowptr, dinv, csr_src
__launch_bounds__(256)
__global__ void radix_build(const int* __restrict__ tmp, const int* __restrict__ bucket_base,
                            int* __restrict__ csr_src, int* __restrict__ rowptr,
                            float* __restrict__ dinv, int N) {
    __shared__ int cnt[BKN], excl[BKN], cur[BKN];
    __shared__ int s[256];
    int b = blockIdx.x, tid = threadIdx.x;
    int beg = bucket_base[b], end = bucket_base[b + 1];
    cnt[tid] = 0; cnt[tid + 256] = 0;
    __syncthreads();
    for (int e = beg + tid; e < end; e += 256)
        atomicAdd(&cnt[(tmp[e] >> 17) & (BKN - 1)], 1);
    __syncthreads();
    int c0 = cnt[2 * tid], c1 = cnt[2 * tid + 1];
    int v = c0 + c1;
    s[tid] = v; __syncthreads();
    for (int off = 1; off < 256; off <<= 1) {
        int t = (tid >= off) ? s[tid - off] : 0;
        __syncthreads();
        s[tid] += t;
        __syncthreads();
    }
    int base2 = s[tid] - v;   // exclusive over bin pairs
    excl[2 * tid] = base2;
    excl[2 * tid + 1] = base2 + c0;
    cur[2 * tid] = 0; cur[2 * tid + 1] = 0;
    int node0 = b << BKSH;
    int n0 = node0 + 2 * tid, n1 = n0 + 1;
    if (n0 < N) { rowptr[n0] = beg + base2;      dinv[n0] = rsqrtf(fmaxf((float)c0, 1.0f)); }
    if (n1 < N) { rowptr[n1] = beg + base2 + c0; dinv[n1] = rsqrtf(fmaxf((float)c1, 1.0f)); }
    __syncthreads();
    for (int e = beg + tid; e < end; e += 256) {
        int vv = tmp[e];
        int dlow = (vv >> 17) & (BKN - 1);
        int pos = excl[dlow] + atomicAdd(&cur[dlow], 1);
        csr_src[beg + pos] = vv & 0x1FFFF;
    }
}

// ============ prescale: Y = bf16(X * dinv[node]) ============
__global__ void prescale(const float* __restrict__ X, const float* __restrict__ dinv,
                         u16* __restrict__ Y, int total4) {   // total4 = N*16
    int i = blockIdx.x * blockDim.x + threadIdx.x;
    if (i < total4) {
        int node = i >> 4;
        float dn = dinv[node];
        float4 v = ((const float4*)X)[i];
        ushort4 y;
        y.x = f2bf(v.x * dn); y.y = f2bf(v.y * dn);
        y.z = f2bf(v.z * dn); y.w = f2bf(v.w * dn);
        ((ushort4*)Y)[i] = y;
    }
}

// ============ SpMM gather (bf16 rows): wave/node, 8 edges/iter, 16B loads ============
__launch_bounds__(256)
__global__ void spmm_bf16(const u16* __restrict__ Y, const int* __restrict__ rowptr,
                          const int* __restrict__ csr_src, const float* __restrict__ dinv,
                          const float* __restrict__ Xprev, float* __restrict__ Xout,
                          u16* __restrict__ Yout, int n, int mode) {
    int node = (blockIdx.x * blockDim.x + threadIdx.x) >> 6;
    if (node >= n) return;
    int lane = threadIdx.x & 63;
    int g = lane >> 3;            // edge subgroup 0..7
    int fl = (lane & 7) << 3;     // feature offset 0,8,...,56

    int beg = rowptr[node], end = rowptr[node + 1];
    float acc[8];
#pragma unroll
    for (int j = 0; j < 8; ++j) acc[j] = 0.f;

    for (int e0 = beg; e0 < end; e0 += 8) {
        int eg = e0 + g;
        if (eg < end) {
            int s = csr_src[eg];
            uint4 u = *(const uint4*)(Y + (size_t)s * NF + fl);
            acc[0] += bf2f(u.x & 0xFFFFu); acc[1] += bf2f(u.x >> 16);
            acc[2] += bf2f(u.y & 0xFFFFu); acc[3] += bf2f(u.y >> 16);
            acc[4] += bf2f(u.z & 0xFFFFu); acc[5] += bf2f(u.z >> 16);
            acc[6] += bf2f(u.w & 0xFFFFu); acc[7] += bf2f(u.w >> 16);
        }
    }
#pragma unroll
    for (int m = 8; m <= 32; m <<= 1) {
#pragma unroll
        for (int j = 0; j < 8; ++j) acc[j] += __shfl_xor(acc[j], m, 64);
    }
    if (g == 0) {
        float dn = dinv[node];
        float r[8];
        if (mode == 1) {
#pragma unroll
            for (int j = 0; j < 8; ++j) r[j] = -acc[j] * dn;
            uint4 uy;
            uy.x = (unsigned)f2bf(r[0] * dn) | ((unsigned)f2bf(r[1] * dn) << 16);
            uy.y = (unsigned)f2bf(r[2] * dn) | ((unsigned)f2bf(r[3] * dn) << 16);
            uy.z = (unsigned)f2bf(r[4] * dn) | ((unsigned)f2bf(r[5] * dn) << 16);
            uy.w = (unsigned)f2bf(r[6] * dn) | ((unsigned)f2bf(r[7] * dn) << 16);
            *(uint4*)(Yout + (size_t)node * NF + fl) = uy;
        } else {
            float4 a = *(const float4*)(Xprev + (size_t)node * NF + fl);
            float4 b = *(const float4*)(Xprev + (size_t)node * NF + fl + 4);
            r[0] = -2.f * acc[0] * dn - a.x; r[1] = -2.f * acc[1] * dn - a.y;
            r[2] = -2.f * acc[2] * dn - a.z; r[3] = -2.f * acc[3] * dn - a.w;
            r[4] = -2.f * acc[4] * dn - b.x; r[5] = -2.f * acc[5] * dn - b.y;
            r[6] = -2.f * acc[6] * dn - b.z; r[7] = -2.f * acc[7] * dn - b.w;
        }
        float4 o0 = make_float4(r[0], r[1], r[2], r[3]);
        float4 o1 = make_float4(r[4], r[5], r[6], r[7]);
        *(float4*)(Xout + (size_t)node * NF + fl) = o0;
        *(float4*)(Xout + (size_t)node * NF + fl + 4) = o1;
    }
}

// ============ GEMM v3: 256 threads / 128 nodes; OUTF split across wave-pairs ============
template <int OUTF>
__launch_bounds__(256)
__global__ void gemm_cheb(const float* __restrict__ X0, const float* __restrict__ X1,
                          const float* __restrict__ X2, const float* __restrict__ W,
                          const float* __restrict__ bias, float* __restrict__ out,
                          const float* __restrict__ dinv, u16* __restrict__ Yout,
                          int n, int do_relu) {
    constexpr int HALF = OUTF / 2;     // 32 or 16
    constexpr int EST = HALF + 1;      // epilogue LDS stride
    __shared__ float xs[128 * 33];
    const int tid = threadIdx.x;
    const int node0 = blockIdx.x * 128;
    const int ln = tid & 127;
    const int ho_u = __builtin_amdgcn_readfirstlane(tid >> 7);  // wave-uniform half idx

    float acc[HALF];
#pragma unroll
    for (int j = 0; j < HALF; ++j) acc[j] = bias[ho_u * HALF + j];

    const float* Xp[3] = {X0, X1, X2};
#pragma unroll 1
    for (int p = 0; p < 3; ++p) {
        const float* __restrict__ Xc = Xp[p];
#pragma unroll 1
        for (int h = 0; h < 2; ++h) {
#pragma unroll
            for (int it = 0; it < 4; ++it) {
                int idx4 = it * 256 + tid;
                int ln2 = idx4 >> 3;
                int k4 = (idx4 & 7) * 4;
                float4 v = make_float4(0.f, 0.f, 0.f, 0.f);
                int gnode = node0 + ln2;
                if (gnode < n) v = *(const float4*)&Xc[(size_t)gnode * 64 + h * 32 + k4];
                float* s = &xs[ln2 * 33 + k4];
                s[0] = v.x; s[1] = v.y; s[2] = v.z; s[3] = v.w;
            }
            __syncthreads();

            const float* __restrict__ Wp =
                W + (size_t)p * 64 * OUTF + (size_t)h * 32 * OUTF + ho_u * HALF;
            for (int k = 0; k < 32; ++k) {
                float x = xs[ln * 33 + k];
#pragma unroll
                for (int j = 0; j < HALF; ++j)
                    acc[j] += x * Wp[k * OUTF + j];
            }
            __syncthreads();
        }
    }

#pragma unroll 1
    for (int hp = 0; hp < 2; ++hp) {
        if (ho_u == hp) {
#pragma unroll
            for (int j = 0; j < HALF; ++j) {
                float v = acc[j];
                if (do_relu) v = fmaxf(v, 0.f);
                xs[ln * EST + j] = v;
            }
        }
        __syncthreads();
        constexpr int NIT = (128 * HALF / 4) / 256;   // 4 (OUTF=64) or 2 (OUTF=32)
#pragma unroll
        for (int it = 0; it < NIT; ++it) {
            int idx4 = it * 256 + tid;
            int ln2 = idx4 / (HALF / 4);
            int k4 = (idx4 % (HALF / 4)) * 4;
            int gnode = node0 + ln2;
            if (gnode < n) {
                const float* s = &xs[ln2 * EST + k4];
                float4 v = make_float4(s[0], s[1], s[2], s[3]);
                *(float4*)&out[(size_t)gnode * OUTF + hp * HALF + k4] = v;
                if (OUTF == 64 && Yout) {
                    float dn = dinv[gnode];
                    ushort4 y;
                    y.x = f2bf(v.x * dn); y.y = f2bf(v.y * dn);
                    y.z = f2bf(v.z * dn); y.w = f2bf(v.w * dn);
                    *(ushort4*)&Yout[(size_t)gnode * OUTF + hp * HALF + k4] = y;
                }
            }
        }
        __syncthreads();
    }
}

extern "C" void kernel_launch(void* const* d_in, const int* in_sizes, int n_in,
                              void* d_out, int out_size, void* d_ws, size_t ws_size,
                              hipStream_t stream) {
    const float* feat = (const float*)d_in[0];
    const int*   src  = (const int*)d_in[1];
    const int*   dst  = (const int*)d_in[2];
    const float* W1   = (const float*)d_in[3];
    const float* b1   = (const float*)d_in[4];
    const float* W2   = (const float*)d_in[5];
    const float* b2   = (const float*)d_in[6];
    float* out = (float*)d_out;

    const int N = in_sizes[0] / NF;   // 100000
    const int E = in_sizes[1];        // 1600000
    const size_t NFtot = (size_t)N * NF;
    const int nbuk = (N + BKN - 1) >> BKSH;   // 196 (must be <= 256)
    const int epb = (E + SB - 1) / SB;        // 6250

    // workspace layout (16B-aligned chunks)
    char* p = (char*)d_ws;
    int* hist         = (int*)p;   p += (size_t)BKN * SB * 4;   // 512 KB
    int* bucket_total = (int*)p;   p += (BKN + 16) * 4;
    int* bucket_base  = (int*)p;   p += (BKN + 16) * 4;
    int* rowptr       = (int*)p;   p += ((size_t)N + 16) * 4;
    int* csr_src      = (int*)p;   p += (size_t)E * 4;
    float* dinv       = (float*)p; p += ((size_t)N + 16) * 4;
    float* X1         = (float*)p; p += NFtot * 4;
    float* X2         = (float*)p; p += NFtot * 4;
    float* H          = (float*)p; p += NFtot * 4;
    u16* Ya           = (u16*)p;   p += NFtot * 2;   // Y0, later YH
    u16* Yb           = (u16*)p;   p += NFtot * 2;   // Y1 (both layers)
    int* tmp = (int*)X1;           // packed edges; consumed before X1 first written

    const int TB = 256;
    dim3 blk(TB);
    dim3 gWave(((size_t)N * 64 + TB - 1) / TB);
    dim3 gPre(((size_t)N * 16 + TB - 1) / TB);
    dim3 gGemm((N + 127) / 128);

    // ---- CSR build (radix partition) ----
    hipMemsetAsync(bucket_total, 0, (size_t)(BKN + 1) * sizeof(int), stream);
    radix_count<<<dim3(SB), blk, 0, stream>>>(dst, hist, bucket_total, E, epb, nbuk);
    bucket_scan<<<1, blk, 0, stream>>>(bucket_total, bucket_base, rowptr, nbuk, E, N);
    hist_scan<<<dim3(nbuk), blk, 0, stream>>>(hist, bucket_base);
    radix_scatter<<<dim3(SB), blk, 0, stream>>>(src, dst, hist, tmp, E, epb, nbuk);
    radix_build<<<dim3(nbuk), blk, 0, stream>>>(tmp, bucket_base, csr_src, rowptr, dinv, N);

    // ---- layer 1 ----
    prescale<<<gPre, blk, 0, stream>>>(feat, dinv, Ya, (int)(N * 16));
    spmm_bf16<<<gWave, blk, 0, stream>>>(Ya, rowptr, csr_src, dinv, nullptr, X1, Yb, N, 1);
    spmm_bf16<<<gWave, blk, 0, stream>>>(Yb, rowptr, csr_src, dinv, feat, X2, nullptr, N, 2);
    gemm_cheb<64><<<gGemm, blk, 0, stream>>>(feat, X1, X2, W1, b1, H, dinv, Ya, N, 1);

    // ---- layer 2 ----
    spmm_bf16<<<gWave, blk, 0, stream>>>(Ya, rowptr, csr_src, dinv, nullptr, X1, Yb, N, 1);
    spmm_bf16<<<gWave, blk, 0, stream>>>(Yb, rowptr, csr_src, dinv, H, X2, nullptr, N, 2);
    gemm_cheb<32><<<gGemm, blk, 0, stream>>>(H, X1, X2, W2, b2, out, dinv, nullptr, N, 0);
}